// Round 1
// 552.557 us; speedup vs baseline: 1.3605x; 1.3605x over previous
//
#include <hip/hip_runtime.h>
#include <hip/hip_bf16.h>

constexpr int kB   = 32;
constexpr int kC   = 256;
constexpr int kHW  = 4096;   // 64*64
constexpr int kC4  = 64;
constexpr int kGC  = 16;
constexpr int kNID = 80;     // 128 - 3*16

__device__ __forceinline__ float gelu_exact(float x) {
    return 0.5f * x * (1.0f + erff(x * 0.70710678118654752440f));
}

__device__ __forceinline__ float4 gelu4(float4 v) {
    return make_float4(gelu_exact(v.x), gelu_exact(v.y), gelu_exact(v.z), gelu_exact(v.w));
}

// ---------------- Kernel 0: init qp accumulator (ws is poisoned 0xAA) ----------------
// kp no longer needs init: conv1x1 head-1 blocks write every kp element directly.
__global__ __launch_bounds__(256) void init_kernel(float4* __restrict__ qp)
{
    size_t i = (size_t)blockIdx.x * 256 + threadIdx.x;   // 524288 float4 = 2,097,152 floats
    qp[i] = make_float4(0.f, 0.f, 0.f, 0.f);
}

// ---------------- Kernel 1: x1 branch (identity + 3 depthwise convs) + GELU ----------------
// All paths float4-vectorized (hipcc does not auto-vectorize scalar fp32 streams).
__global__ __launch_bounds__(256) void part1_kernel(
    const float* __restrict__ x,
    const float* __restrict__ w_hw, const float* __restrict__ b_hw,
    const float* __restrict__ w_w,  const float* __restrict__ b_w,
    const float* __restrict__ w_h,  const float* __restrict__ b_h,
    float* __restrict__ out)
{
    int bc = blockIdx.x;            // b*128 + c
    int b  = bc >> 7;
    int c  = bc & 127;
    const float4* xp4 = (const float4*)(x   + (size_t)(b * kC + c) * kHW);
    float4*       op4 = (float4*)      (out + (size_t)(b * kC + c) * kHW);
    int tid = threadIdx.x;

    if (c < kNID) {
        for (int q = tid; q < 1024; q += 256)
            op4[q] = gelu4(xp4[q]);
    } else if (c < kNID + kGC) {           // 3x3 dwconv, pad 1
        int g = c - kNID;
        float wv[9];
        #pragma unroll
        for (int j = 0; j < 9; ++j) wv[j] = w_hw[g * 9 + j];
        float bias = b_hw[g];
        for (int q = tid; q < 1024; q += 256) {
            int h = q >> 4, wq = q & 15;
            float ax = bias, ay = bias, az = bias, aw = bias;
            #pragma unroll
            for (int dy = -1; dy <= 1; ++dy) {
                int rr = h + dy;
                if ((unsigned)rr >= 64u) continue;
                int base = rr * 16;
                float  l  = (wq > 0)  ? xp4[base + wq - 1].w : 0.f;
                float4 Bv = xp4[base + wq];
                float  r  = (wq < 15) ? xp4[base + wq + 1].x : 0.f;
                float w0 = wv[(dy + 1) * 3 + 0];
                float w1 = wv[(dy + 1) * 3 + 1];
                float w2 = wv[(dy + 1) * 3 + 2];
                ax += w0 * l    + w1 * Bv.x + w2 * Bv.y;
                ay += w0 * Bv.x + w1 * Bv.y + w2 * Bv.z;
                az += w0 * Bv.y + w1 * Bv.z + w2 * Bv.w;
                aw += w0 * Bv.z + w1 * Bv.w + w2 * r;
            }
            op4[q] = make_float4(gelu_exact(ax), gelu_exact(ay), gelu_exact(az), gelu_exact(aw));
        }
    } else if (c < kNID + 2 * kGC) {       // 1x11 dwconv, pad (0,5)
        int g = c - (kNID + kGC);
        float wv[11];
        #pragma unroll
        for (int j = 0; j < 11; ++j) wv[j] = w_w[g * 11 + j];
        float bias = b_w[g];
        for (int q = tid; q < 1024; q += 256) {
            int h = q >> 4, wq = q & 15;
            int base = h * 16;
            float f[20];
            #pragma unroll
            for (int m = 0; m < 5; ++m) {
                int qq = wq + m - 2;
                float4 v;
                if ((unsigned)qq < 16u) v = xp4[base + qq];
                else                    v = make_float4(0.f, 0.f, 0.f, 0.f);
                f[4 * m + 0] = v.x; f[4 * m + 1] = v.y;
                f[4 * m + 2] = v.z; f[4 * m + 3] = v.w;
            }
            float a0 = bias, a1 = bias, a2 = bias, a3 = bias;
            #pragma unroll
            for (int m = 0; m < 11; ++m) {
                float w = wv[m];
                a0 += w * f[m + 3];
                a1 += w * f[m + 4];
                a2 += w * f[m + 5];
                a3 += w * f[m + 6];
            }
            op4[q] = make_float4(gelu_exact(a0), gelu_exact(a1), gelu_exact(a2), gelu_exact(a3));
        }
    } else {                               // 11x1 dwconv, pad (5,0)
        int g = c - (kNID + 2 * kGC);
        float wv[11];
        #pragma unroll
        for (int j = 0; j < 11; ++j) wv[j] = w_h[g * 11 + j];
        float bias = b_h[g];
        for (int q = tid; q < 1024; q += 256) {
            int h = q >> 4, wq = q & 15;
            float a0 = bias, a1 = bias, a2 = bias, a3 = bias;
            #pragma unroll
            for (int m = 0; m < 11; ++m) {
                int rr = h + m - 5;
                if ((unsigned)rr < 64u) {
                    float4 v = xp4[rr * 16 + wq];
                    float w = wv[m];
                    a0 += w * v.x; a1 += w * v.y; a2 += w * v.z; a3 += w * v.w;
                }
            }
            op4[q] = make_float4(gelu_exact(a0), gelu_exact(a1), gelu_exact(a2), gelu_exact(a3));
        }
    }
}

// ---------------- Kernel 2: 1x1 conv GEMM + GELU + pooling ----------------
// Grid: (32 pixel-blocks of 128 px = 2 image rows, 4 heads, B). Block 256.
// Tile: o=64 (one head) x p=128, per-thread 4x8 acc -> 32 FMA per 3 ds_read_b128.
// 2 image rows per block => 2x2 k-maxpool is block-local (direct store, no atomics,
// no kp init); q-pool needs <=2 atomicAdds per cell (own row + partial to next).
__global__ __launch_bounds__(256, 3) void conv1x1_kernel(
    const float* __restrict__ x,
    const float* __restrict__ w_qkvl, const float* __restrict__ b_qkvl,
    float* __restrict__ qp, float* __restrict__ kp,
    float* __restrict__ out)
{
    __shared__ float Ws[64][68];    // [k][o], +4 pad
    __shared__ float Xs[64][128];   // [k][p]; reused as Ys[o][p] in epilogue
    int pb   = blockIdx.x;          // 0..31
    int p0   = pb * 128;
    int head = blockIdx.y;
    int o0   = head * 64;
    int b    = blockIdx.z;
    int t    = threadIdx.x;
    int to   = t >> 4;              // 0..15, 4 o each
    int tp   = t & 15;              // 0..15, 8 p each

    float acc[4][8] = {};
    for (int kc = 0; kc < 2; ++kc) {
        #pragma unroll
        for (int r = 0; r < 4; ++r) {            // stage W tile: 64 o x 64 k
            int g = t + r * 256;                 // 0..1023
            int o = g & 63, kq = g >> 6;         // kq 0..15
            float4 w4 = *(const float4*)&w_qkvl[(size_t)(o0 + o) * 128 + kc * 64 + kq * 4];
            Ws[kq * 4 + 0][o] = w4.x;
            Ws[kq * 4 + 1][o] = w4.y;
            Ws[kq * 4 + 2][o] = w4.z;
            Ws[kq * 4 + 3][o] = w4.w;
        }
        #pragma unroll
        for (int r = 0; r < 8; ++r) {            // stage X tile: 64 k x 128 p (float4)
            int g = t + r * 256;                 // 0..2047
            int k = g >> 5, p4 = g & 31;
            *(float4*)&Xs[k][p4 * 4] =
                *(const float4*)&x[(size_t)(b * kC + 128 + kc * 64 + k) * kHW + p0 + p4 * 4];
        }
        __syncthreads();
        #pragma unroll 4
        for (int k = 0; k < 64; ++k) {
            float4 wv = *(const float4*)&Ws[k][to * 4];
            float4 xa = *(const float4*)&Xs[k][tp * 8];
            float4 xb = *(const float4*)&Xs[k][tp * 8 + 4];
            float w4[4] = {wv.x, wv.y, wv.z, wv.w};
            float x8[8] = {xa.x, xa.y, xa.z, xa.w, xb.x, xb.y, xb.z, xb.w};
            #pragma unroll
            for (int i = 0; i < 4; ++i)
                #pragma unroll
                for (int j = 0; j < 8; ++j)
                    acc[i][j] += w4[i] * x8[j];
        }
        __syncthreads();
    }

    if (head < 2) {
        // stage GELU outputs Ys[o][p] into Xs (safe: sync'd after last compute)
        #pragma unroll
        for (int i = 0; i < 4; ++i) {
            int o = to * 4 + i;
            float bias = b_qkvl[o0 + o];
            float4 ya = make_float4(gelu_exact(acc[i][0] + bias), gelu_exact(acc[i][1] + bias),
                                    gelu_exact(acc[i][2] + bias), gelu_exact(acc[i][3] + bias));
            float4 yb = make_float4(gelu_exact(acc[i][4] + bias), gelu_exact(acc[i][5] + bias),
                                    gelu_exact(acc[i][6] + bias), gelu_exact(acc[i][7] + bias));
            *(float4*)&Xs[o][tp * 8]     = ya;
            *(float4*)&Xs[o][tp * 8 + 4] = yb;
        }
        __syncthreads();
        if (head == 0) {
            // q: 3x3 s2 p1 avg-pool. Rows 2pb,2pb+1 in-block: full horiz sums per row,
            // (s0+s1)/9 -> pool row pb; s1/9 -> pool row pb+1 (row 2pb+1 = 2(pb+1)-1).
            bool ey = (pb + 1 < 32);
            for (int e = t; e < 2048; e += 256) {
                int ch = e >> 5, mx = e & 31;
                const float* Y0 = &Xs[ch][0];
                const float* Y1 = &Xs[ch][64];
                float s0 = Y0[2 * mx] + Y0[2 * mx + 1] + (mx > 0 ? Y0[2 * mx - 1] : 0.f);
                float s1 = Y1[2 * mx] + Y1[2 * mx + 1] + (mx > 0 ? Y1[2 * mx - 1] : 0.f);
                float* dst = &qp[(((size_t)(b * kC4 + ch)) << 10) + pb * 32 + mx];
                atomicAdd(dst, (s0 + s1) * (1.0f / 9.0f));
                if (ey) atomicAdd(dst + 32, s1 * (1.0f / 9.0f));
            }
        } else {
            // k: 2x2 s2 max-pool, entirely block-local -> direct store
            for (int e = t; e < 2048; e += 256) {
                int ch = e >> 5, mx = e & 31;
                const float* Y0 = &Xs[ch][0];
                const float* Y1 = &Xs[ch][64];
                float m = fmaxf(fmaxf(Y0[2 * mx], Y0[2 * mx + 1]),
                                fmaxf(Y1[2 * mx], Y1[2 * mx + 1]));
                kp[(((size_t)(b * kC4 + ch)) << 10) + pb * 32 + mx] = m;
            }
        }
    } else {
        // v -> out ch 192..255 (temp storage), lfeat -> out ch 128..191
        int cbase = (head == 2) ? 192 : 128;
        #pragma unroll
        for (int i = 0; i < 4; ++i) {
            int o = to * 4 + i;
            float bias = b_qkvl[o0 + o];
            float4 ya = make_float4(gelu_exact(acc[i][0] + bias), gelu_exact(acc[i][1] + bias),
                                    gelu_exact(acc[i][2] + bias), gelu_exact(acc[i][3] + bias));
            float4 yb = make_float4(gelu_exact(acc[i][4] + bias), gelu_exact(acc[i][5] + bias),
                                    gelu_exact(acc[i][6] + bias), gelu_exact(acc[i][7] + bias));
            float* dst = &out[(size_t)(b * kC + cbase + o) * kHW + p0 + tp * 8];
            *(float4*)dst       = ya;
            *(float4*)(dst + 4) = yb;
        }
    }
}

// ---------------- Kernel 3: qk = qf @ kf^T (sum over 1024), softmax over c ----------------
__global__ __launch_bounds__(256) void qk_softmax_kernel(
    const float* __restrict__ qp, const float* __restrict__ kp,
    float* __restrict__ attn)
{
    __shared__ float qs[64][129];
    __shared__ float ks[16][129];
    __shared__ float qk_s[64][17];
    __shared__ float mx[16], sm[16];
    int dt = blockIdx.x;
    int b  = blockIdx.y;
    int t  = threadIdx.x;
    int c  = t & 63, dg = t >> 6;

    float acc[4] = {};
    for (int nc = 0; nc < 8; ++nc) {
        #pragma unroll
        for (int r = 0; r < 32; ++r) {
            int g = t + r * 256;
            int cc = g >> 7, n = g & 127;
            qs[cc][n] = qp[(size_t)(b * 64 + cc) * 1024 + nc * 128 + n];
        }
        #pragma unroll
        for (int r = 0; r < 8; ++r) {
            int g = t + r * 256;
            int dl = g >> 7, n = g & 127;
            ks[dl][n] = kp[(size_t)(b * 64 + dt * 16 + dl) * 1024 + nc * 128 + n];
        }
        __syncthreads();
        for (int n = 0; n < 128; ++n) {
            float qv = qs[c][n];
            #pragma unroll
            for (int j = 0; j < 4; ++j)
                acc[j] += qv * ks[dg * 4 + j][n];
        }
        __syncthreads();
    }
    #pragma unroll
    for (int j = 0; j < 4; ++j) qk_s[c][dg * 4 + j] = acc[j];
    __syncthreads();
    if (t < 16) {
        float m = -1e30f;
        for (int cc = 0; cc < 64; ++cc) m = fmaxf(m, qk_s[cc][t]);
        float s = 0.f;
        for (int cc = 0; cc < 64; ++cc) s += expf(qk_s[cc][t] - m);
        mx[t] = m;
        sm[t] = 1.0f / s;
    }
    __syncthreads();
    #pragma unroll
    for (int j = 0; j < 4; ++j) {
        int d = dg * 4 + j;
        attn[(size_t)(b * 64 + c) * 64 + dt * 16 + d] = expf(acc[j] - mx[d]) * sm[d];
    }
}

// ---------------- Kernel 4: out[b,192+d,m] = sum_c attn[b,c,d] * v[b,c,m] ----------------
__global__ __launch_bounds__(256) void out2_kernel(
    const float* __restrict__ attn, float* __restrict__ out)
{
    __shared__ float at[64][64];   // [c][d]
    int b = blockIdx.y;
    int t = threadIdx.x;
    #pragma unroll
    for (int r = 0; r < 16; ++r) {
        int g = t + r * 256;
        at[g >> 6][g & 63] = attn[(size_t)b * 4096 + g];
    }
    __syncthreads();
    int m = blockIdx.x * 256 + t;
    float* vcol = out + (size_t)(b * kC + 192) * kHW + m;   // stride kHW per channel
    float vreg[64];
    #pragma unroll
    for (int cc = 0; cc < 64; ++cc) vreg[cc] = vcol[(size_t)cc * kHW];
    float acc[64] = {};
    for (int cc = 0; cc < 64; ++cc) {
        float vv = vreg[cc];
        #pragma unroll
        for (int d4 = 0; d4 < 16; ++d4) {
            float4 a = *(const float4*)&at[cc][d4 * 4];
            acc[d4 * 4 + 0] += a.x * vv;
            acc[d4 * 4 + 1] += a.y * vv;
            acc[d4 * 4 + 2] += a.z * vv;
            acc[d4 * 4 + 3] += a.w * vv;
        }
    }
    #pragma unroll
    for (int d = 0; d < 64; ++d)
        vcol[(size_t)d * kHW] = acc[d];
}

extern "C" void kernel_launch(void* const* d_in, const int* in_sizes, int n_in,
                              void* d_out, int out_size, void* d_ws, size_t ws_size,
                              hipStream_t stream)
{
    const float* x      = (const float*)d_in[0];
    const float* w_hw   = (const float*)d_in[1];
    const float* b_hw   = (const float*)d_in[2];
    const float* w_w    = (const float*)d_in[3];
    const float* b_w    = (const float*)d_in[4];
    const float* w_h    = (const float*)d_in[5];
    const float* b_h    = (const float*)d_in[6];
    const float* w_qkvl = (const float*)d_in[7];
    const float* b_qkvl = (const float*)d_in[8];
    float* out = (float*)d_out;

    // Workspace layout (~17.3 MB): qp fp32 | kp fp32 | attn fp32
    char* w = (char*)d_ws;
    float* qp   = (float*)w;  w += (size_t)kB * kC4 * 1024 * 4;   // 8.39 MB
    float* kp   = (float*)w;  w += (size_t)kB * kC4 * 1024 * 4;   // 8.39 MB
    float* attn = (float*)w;  w += (size_t)kB * kC4 * kC4 * 4;    // 0.52 MB

    init_kernel<<<dim3(2048), 256, 0, stream>>>((float4*)qp);
    part1_kernel<<<dim3(kB * 128), 256, 0, stream>>>(x, w_hw, b_hw, w_w, b_w, w_h, b_h, out);
    conv1x1_kernel<<<dim3(32, 4, kB), 256, 0, stream>>>(x, w_qkvl, b_qkvl, qp, kp, out);
    qk_softmax_kernel<<<dim3(4, kB), 256, 0, stream>>>(qp, kp, attn);
    out2_kernel<<<dim3(16, kB), 256, 0, stream>>>(attn, out);
}

// Round 2
// 484.733 us; speedup vs baseline: 1.5509x; 1.1399x over previous
//
#include <hip/hip_runtime.h>
#include <hip/hip_bf16.h>

constexpr int kB   = 32;
constexpr int kC   = 256;
constexpr int kHW  = 4096;   // 64*64
constexpr int kC4  = 64;
constexpr int kGC  = 16;
constexpr int kNID = 80;     // 128 - 3*16

__device__ __forceinline__ float gelu_exact(float x) {
    return 0.5f * x * (1.0f + erff(x * 0.70710678118654752440f));
}

__device__ __forceinline__ float4 gelu4(float4 v) {
    return make_float4(gelu_exact(v.x), gelu_exact(v.y), gelu_exact(v.z), gelu_exact(v.w));
}

// ---------------- Kernel 0: init qp accumulator (ws is poisoned 0xAA) ----------------
// kp needs no init: conv1x1 head-1 blocks write every kp element directly.
__global__ __launch_bounds__(256) void init_kernel(float4* __restrict__ qp)
{
    size_t i = (size_t)blockIdx.x * 256 + threadIdx.x;   // 524288 float4 = 2,097,152 floats
    qp[i] = make_float4(0.f, 0.f, 0.f, 0.f);
}

// ---------------- Kernel 1: x1 branch (identity + 3 depthwise convs) + GELU ----------------
__global__ __launch_bounds__(256) void part1_kernel(
    const float* __restrict__ x,
    const float* __restrict__ w_hw, const float* __restrict__ b_hw,
    const float* __restrict__ w_w,  const float* __restrict__ b_w,
    const float* __restrict__ w_h,  const float* __restrict__ b_h,
    float* __restrict__ out)
{
    int bc = blockIdx.x;            // b*128 + c
    int b  = bc >> 7;
    int c  = bc & 127;
    const float4* xp4 = (const float4*)(x   + (size_t)(b * kC + c) * kHW);
    float4*       op4 = (float4*)      (out + (size_t)(b * kC + c) * kHW);
    int tid = threadIdx.x;

    if (c < kNID) {
        for (int q = tid; q < 1024; q += 256)
            op4[q] = gelu4(xp4[q]);
    } else if (c < kNID + kGC) {           // 3x3 dwconv, pad 1
        int g = c - kNID;
        float wv[9];
        #pragma unroll
        for (int j = 0; j < 9; ++j) wv[j] = w_hw[g * 9 + j];
        float bias = b_hw[g];
        for (int q = tid; q < 1024; q += 256) {
            int h = q >> 4, wq = q & 15;
            float ax = bias, ay = bias, az = bias, aw = bias;
            #pragma unroll
            for (int dy = -1; dy <= 1; ++dy) {
                int rr = h + dy;
                if ((unsigned)rr >= 64u) continue;
                int base = rr * 16;
                float  l  = (wq > 0)  ? xp4[base + wq - 1].w : 0.f;
                float4 Bv = xp4[base + wq];
                float  r  = (wq < 15) ? xp4[base + wq + 1].x : 0.f;
                float w0 = wv[(dy + 1) * 3 + 0];
                float w1 = wv[(dy + 1) * 3 + 1];
                float w2 = wv[(dy + 1) * 3 + 2];
                ax += w0 * l    + w1 * Bv.x + w2 * Bv.y;
                ay += w0 * Bv.x + w1 * Bv.y + w2 * Bv.z;
                az += w0 * Bv.y + w1 * Bv.z + w2 * Bv.w;
                aw += w0 * Bv.z + w1 * Bv.w + w2 * r;
            }
            op4[q] = make_float4(gelu_exact(ax), gelu_exact(ay), gelu_exact(az), gelu_exact(aw));
        }
    } else if (c < kNID + 2 * kGC) {       // 1x11 dwconv, pad (0,5)
        int g = c - (kNID + kGC);
        float wv[11];
        #pragma unroll
        for (int j = 0; j < 11; ++j) wv[j] = w_w[g * 11 + j];
        float bias = b_w[g];
        for (int q = tid; q < 1024; q += 256) {
            int h = q >> 4, wq = q & 15;
            int base = h * 16;
            float f[20];
            #pragma unroll
            for (int m = 0; m < 5; ++m) {
                int qq = wq + m - 2;
                float4 v;
                if ((unsigned)qq < 16u) v = xp4[base + qq];
                else                    v = make_float4(0.f, 0.f, 0.f, 0.f);
                f[4 * m + 0] = v.x; f[4 * m + 1] = v.y;
                f[4 * m + 2] = v.z; f[4 * m + 3] = v.w;
            }
            float a0 = bias, a1 = bias, a2 = bias, a3 = bias;
            #pragma unroll
            for (int m = 0; m < 11; ++m) {
                float w = wv[m];
                a0 += w * f[m + 3];
                a1 += w * f[m + 4];
                a2 += w * f[m + 5];
                a3 += w * f[m + 6];
            }
            op4[q] = make_float4(gelu_exact(a0), gelu_exact(a1), gelu_exact(a2), gelu_exact(a3));
        }
    } else {                               // 11x1 dwconv, pad (5,0)
        int g = c - (kNID + 2 * kGC);
        float wv[11];
        #pragma unroll
        for (int j = 0; j < 11; ++j) wv[j] = w_h[g * 11 + j];
        float bias = b_h[g];
        for (int q = tid; q < 1024; q += 256) {
            int h = q >> 4, wq = q & 15;
            float a0 = bias, a1 = bias, a2 = bias, a3 = bias;
            #pragma unroll
            for (int m = 0; m < 11; ++m) {
                int rr = h + m - 5;
                if ((unsigned)rr < 64u) {
                    float4 v = xp4[rr * 16 + wq];
                    float w = wv[m];
                    a0 += w * v.x; a1 += w * v.y; a2 += w * v.z; a3 += w * v.w;
                }
            }
            op4[q] = make_float4(gelu_exact(a0), gelu_exact(a1), gelu_exact(a2), gelu_exact(a3));
        }
    }
}

// ---------------- Kernel 2: 1x1 conv GEMM + GELU + pooling ----------------
// Grid: (16 pixel-blocks of 256 px = 4 image rows, 4 heads, B). Block 256.
// Tile: o=64 x p=256, per-thread 8x8 acc -> 64 FMA per 4 ds_read_b128.
// K chunked by 32: LDS = Ws 32x64 (8KB) + Xs 32x256 (32KB) = 40KB -> 4 blocks/CU.
// Xs layout per row k: [even float4 chunks | odd float4 chunks] so both compute
// reads are contiguous 512B (minimal bank aliasing).
// 4 rows/block: both k-maxpool rows block-local (direct store, no atomics/init);
// q-pool: 1 direct store + 2 atomicAdds per pool-row pair.
__global__ __launch_bounds__(256, 4) void conv1x1_kernel(
    const float* __restrict__ x,
    const float* __restrict__ w_qkvl, const float* __restrict__ b_qkvl,
    float* __restrict__ qp, float* __restrict__ kp,
    float* __restrict__ out)
{
    __shared__ float Ws[32][64];     // [k][o]
    __shared__ float Xs[32 * 256];   // row k at k*256; reused as Ps[64][4][32] in epilogue
    int pb   = blockIdx.x;           // 0..15
    int p0   = pb * 256;
    int head = blockIdx.y;
    int o0   = head * 64;
    int b    = blockIdx.z;
    int t    = threadIdx.x;
    int og   = t >> 5;               // 0..7 : o = og*8 + i
    int tp   = t & 31;               // 0..31: p = tp*8 + j

    float acc[8][8] = {};
    for (int kc = 0; kc < 4; ++kc) {
        // stage W: 32k x 64o (each task = 4 consecutive k for one o)
        #pragma unroll
        for (int r = 0; r < 2; ++r) {
            int g = t + r * 256;                 // 0..511
            int o = g & 63, kq = g >> 6;         // kq 0..7
            float4 w4 = *(const float4*)&w_qkvl[(size_t)(o0 + o) * 128 + kc * 32 + kq * 4];
            Ws[kq * 4 + 0][o] = w4.x;
            Ws[kq * 4 + 1][o] = w4.y;
            Ws[kq * 4 + 2][o] = w4.z;
            Ws[kq * 4 + 3][o] = w4.w;
        }
        // stage X: 32k x 256p float4, even/odd chunk deinterleave
        #pragma unroll
        for (int r = 0; r < 8; ++r) {
            int g = t + r * 256;                 // 0..2047
            int k = g >> 6, cch = g & 63;        // cch = orig float4 chunk
            int cph = (cch >> 1) + (cch & 1) * 32;
            *(float4*)&Xs[k * 256 + cph * 4] =
                *(const float4*)&x[(size_t)(b * kC + 128 + kc * 32 + k) * kHW + p0 + cch * 4];
        }
        __syncthreads();
        for (int k = 0; k < 32; ++k) {
            const float* xrow = &Xs[k * 256];
            float4 wa = *(const float4*)&Ws[k][og * 8];
            float4 wb = *(const float4*)&Ws[k][og * 8 + 4];
            float4 xa = *(const float4*)&xrow[tp * 4];         // pixels tp*8..+3
            float4 xb = *(const float4*)&xrow[128 + tp * 4];   // pixels tp*8+4..+7
            float w8[8] = {wa.x, wa.y, wa.z, wa.w, wb.x, wb.y, wb.z, wb.w};
            float x8[8] = {xa.x, xa.y, xa.z, xa.w, xb.x, xb.y, xb.z, xb.w};
            #pragma unroll
            for (int i = 0; i < 8; ++i)
                #pragma unroll
                for (int j = 0; j < 8; ++j)
                    acc[i][j] += w8[i] * x8[j];
        }
        __syncthreads();
    }

    if (head < 2) {
        // per-thread horizontal pooling in registers, then tiny LDS combine.
        float* Ps = &Xs[0];            // [o][r][m] : o*128 + r*32 + m
        int r  = tp >> 3;              // image row within tile (0..3)
        int m0 = (tp & 7) * 4;         // first pool cell
        #pragma unroll
        for (int i = 0; i < 8; ++i) {
            int o = og * 8 + i;
            float bias = b_qkvl[o0 + o];
            float y[8];
            #pragma unroll
            for (int j = 0; j < 8; ++j) y[j] = gelu_exact(acc[i][j] + bias);
            float s[4];
            if (head == 0) {           // 3-wide sums (pad-1 left), stride 2
                float left = __shfl_up(y[7], 1);
                if ((tp & 7) == 0) left = 0.0f;
                s[0] = left + y[0] + y[1];
                s[1] = y[1] + y[2] + y[3];
                s[2] = y[3] + y[4] + y[5];
                s[3] = y[5] + y[6] + y[7];
            } else {                   // 2-wide max, stride 2
                s[0] = fmaxf(y[0], y[1]);
                s[1] = fmaxf(y[2], y[3]);
                s[2] = fmaxf(y[4], y[5]);
                s[3] = fmaxf(y[6], y[7]);
            }
            *(float4*)&Ps[o * 128 + r * 32 + m0] = *(float4*)s;
        }
        __syncthreads();
        if (head == 0) {
            bool last = (pb == 15);
            for (int e = t; e < 2048; e += 256) {
                int o = e >> 5, m = e & 31;
                const float* P = &Ps[o * 128 + m];
                float pv0 = P[0], pv1 = P[32], pv2 = P[64], pv3 = P[96];
                float* dst = &qp[(((size_t)(b * kC4 + o)) << 10) + (2 * pb) * 32 + m];
                dst[32] = (pv1 + pv2 + pv3) * (1.0f / 9.0f);          // pool row 2pb+1: fully local
                atomicAdd(dst, (pv0 + pv1) * (1.0f / 9.0f));          // pool row 2pb (rows r0,r1)
                if (!last) atomicAdd(dst + 64, pv3 * (1.0f / 9.0f));  // row r3 -> pool row 2pb+2
            }
        } else {
            for (int e = t; e < 2048; e += 256) {
                int o = e >> 5, m = e & 31;
                const float* P = &Ps[o * 128 + m];
                float* dst = &kp[(((size_t)(b * kC4 + o)) << 10) + (2 * pb) * 32 + m];
                dst[0]  = fmaxf(P[0],  P[32]);
                dst[32] = fmaxf(P[64], P[96]);
            }
        }
    } else {
        // v -> out ch 192..255 (temp storage), lfeat -> out ch 128..191
        int cbase = (head == 2) ? 192 : 128;
        #pragma unroll
        for (int i = 0; i < 8; ++i) {
            int o = og * 8 + i;
            float bias = b_qkvl[o0 + o];
            float4 ya = make_float4(gelu_exact(acc[i][0] + bias), gelu_exact(acc[i][1] + bias),
                                    gelu_exact(acc[i][2] + bias), gelu_exact(acc[i][3] + bias));
            float4 yb = make_float4(gelu_exact(acc[i][4] + bias), gelu_exact(acc[i][5] + bias),
                                    gelu_exact(acc[i][6] + bias), gelu_exact(acc[i][7] + bias));
            float* dst = &out[(size_t)(b * kC + cbase + o) * kHW + p0 + tp * 8];
            *(float4*)dst       = ya;
            *(float4*)(dst + 4) = yb;
        }
    }
}

// ---------------- Kernel 3: qk = qf @ kf^T (sum over 1024), softmax over c ----------------
// float4 qs reads (row stride 132) + b128 broadcast ksT reads: 5 LDS instr / 16 FMA.
__global__ __launch_bounds__(256) void qk_softmax_kernel(
    const float* __restrict__ qp, const float* __restrict__ kp,
    float* __restrict__ attn)
{
    __shared__ float qs[64][132];    // 33.8 KB, float4-aligned rows
    __shared__ float ksT[128][20];   // 10 KB   [n][d], float4-aligned rows
    __shared__ float qk_s[64][17];
    __shared__ float mx[16], sm[16];
    int dt = blockIdx.x;
    int b  = blockIdx.y;
    int t  = threadIdx.x;
    int c  = t & 63, dg = t >> 6;

    float acc[4] = {};
    for (int nc = 0; nc < 8; ++nc) {
        #pragma unroll
        for (int r = 0; r < 8; ++r) {            // stage qs: 64c x 128n as float4
            int g = t + r * 256;                 // 0..2047
            int cc = g >> 5, n4 = g & 31;
            *(float4*)&qs[cc][n4 * 4] =
                *(const float4*)&qp[(size_t)(b * 64 + cc) * 1024 + nc * 128 + n4 * 4];
        }
        #pragma unroll
        for (int r = 0; r < 8; ++r) {            // stage ksT transposed: [n][d]
            int g = t + r * 256;
            int dl = g >> 7, n = g & 127;
            ksT[n][dl] = kp[(size_t)(b * 64 + dt * 16 + dl) * 1024 + nc * 128 + n];
        }
        __syncthreads();
        for (int n4 = 0; n4 < 32; ++n4) {
            float4 qv = *(const float4*)&qs[c][n4 * 4];
            float4 k0 = *(const float4*)&ksT[n4 * 4 + 0][dg * 4];
            float4 k1 = *(const float4*)&ksT[n4 * 4 + 1][dg * 4];
            float4 k2 = *(const float4*)&ksT[n4 * 4 + 2][dg * 4];
            float4 k3 = *(const float4*)&ksT[n4 * 4 + 3][dg * 4];
            acc[0] += qv.x * k0.x + qv.y * k1.x + qv.z * k2.x + qv.w * k3.x;
            acc[1] += qv.x * k0.y + qv.y * k1.y + qv.z * k2.y + qv.w * k3.y;
            acc[2] += qv.x * k0.z + qv.y * k1.z + qv.z * k2.z + qv.w * k3.z;
            acc[3] += qv.x * k0.w + qv.y * k1.w + qv.z * k2.w + qv.w * k3.w;
        }
        __syncthreads();
    }
    #pragma unroll
    for (int j = 0; j < 4; ++j) qk_s[c][dg * 4 + j] = acc[j];
    __syncthreads();
    if (t < 16) {
        float m = -1e30f;
        for (int cc = 0; cc < 64; ++cc) m = fmaxf(m, qk_s[cc][t]);
        float s = 0.f;
        for (int cc = 0; cc < 64; ++cc) s += expf(qk_s[cc][t] - m);
        mx[t] = m;
        sm[t] = 1.0f / s;
    }
    __syncthreads();
    #pragma unroll
    for (int j = 0; j < 4; ++j) {
        int d = dg * 4 + j;
        attn[(size_t)(b * 64 + c) * 64 + dt * 16 + d] = expf(acc[j] - mx[d]) * sm[d];
    }
}

// ---------------- Kernel 4: out[b,192+d,m] = sum_c attn[b,c,d] * v[b,c,m] ----------------
// Chunked v-loads with static indexing (no runtime-indexed reg array -> no scratch).
__global__ __launch_bounds__(256) void out2_kernel(
    const float* __restrict__ attn, float* __restrict__ out)
{
    __shared__ float at[64][64];   // [c][d]
    int b = blockIdx.y;
    int t = threadIdx.x;
    #pragma unroll
    for (int r = 0; r < 4; ++r) {
        int g = t + r * 256;       // 0..1023 float4 tasks
        *(float4*)&at[g >> 4][(g & 15) * 4] = *(const float4*)&attn[(size_t)b * 4096 + g * 4];
    }
    __syncthreads();
    int m = blockIdx.x * 256 + t;
    float* vcol = out + (size_t)(b * kC + 192) * kHW + m;   // stride kHW per channel
    float acc[64] = {};
    for (int c8 = 0; c8 < 8; ++c8) {
        float v[8];
        #pragma unroll
        for (int j = 0; j < 8; ++j) v[j] = vcol[(size_t)(c8 * 8 + j) * kHW];
        #pragma unroll
        for (int j = 0; j < 8; ++j) {
            float vv = v[j];
            const float* arow = &at[c8 * 8 + j][0];
            #pragma unroll
            for (int d4 = 0; d4 < 16; ++d4) {
                float4 a = *(const float4*)&arow[d4 * 4];
                acc[d4 * 4 + 0] += a.x * vv;
                acc[d4 * 4 + 1] += a.y * vv;
                acc[d4 * 4 + 2] += a.z * vv;
                acc[d4 * 4 + 3] += a.w * vv;
            }
        }
    }
    #pragma unroll
    for (int d = 0; d < 64; ++d)
        vcol[(size_t)d * kHW] = acc[d];
}

extern "C" void kernel_launch(void* const* d_in, const int* in_sizes, int n_in,
                              void* d_out, int out_size, void* d_ws, size_t ws_size,
                              hipStream_t stream)
{
    const float* x      = (const float*)d_in[0];
    const float* w_hw   = (const float*)d_in[1];
    const float* b_hw   = (const float*)d_in[2];
    const float* w_w    = (const float*)d_in[3];
    const float* b_w    = (const float*)d_in[4];
    const float* w_h    = (const float*)d_in[5];
    const float* b_h    = (const float*)d_in[6];
    const float* w_qkvl = (const float*)d_in[7];
    const float* b_qkvl = (const float*)d_in[8];
    float* out = (float*)d_out;

    // Workspace layout (~17.3 MB): qp fp32 | kp fp32 | attn fp32
    char* w = (char*)d_ws;
    float* qp   = (float*)w;  w += (size_t)kB * kC4 * 1024 * 4;   // 8.39 MB
    float* kp   = (float*)w;  w += (size_t)kB * kC4 * 1024 * 4;   // 8.39 MB
    float* attn = (float*)w;  w += (size_t)kB * kC4 * kC4 * 4;    // 0.52 MB

    init_kernel<<<dim3(2048), 256, 0, stream>>>((float4*)qp);
    part1_kernel<<<dim3(kB * 128), 256, 0, stream>>>(x, w_hw, b_hw, w_w, b_w, w_h, b_h, out);
    conv1x1_kernel<<<dim3(16, 4, kB), 256, 0, stream>>>(x, w_qkvl, b_qkvl, qp, kp, out);
    qk_softmax_kernel<<<dim3(4, kB), 256, 0, stream>>>(qp, kp, attn);
    out2_kernel<<<dim3(16, kB), 256, 0, stream>>>(attn, out);
}

// Round 3
// 451.840 us; speedup vs baseline: 1.6638x; 1.0728x over previous
//
#include <hip/hip_runtime.h>
#include <hip/hip_bf16.h>

constexpr int kB   = 32;
constexpr int kC   = 256;
constexpr int kHW  = 4096;   // 64*64
constexpr int kC4  = 64;
constexpr int kGC  = 16;
constexpr int kNID = 80;     // 128 - 3*16

__device__ __forceinline__ float gelu_exact(float x) {
    return 0.5f * x * (1.0f + erff(x * 0.70710678118654752440f));
}

__device__ __forceinline__ float4 gelu4(float4 v) {
    return make_float4(gelu_exact(v.x), gelu_exact(v.y), gelu_exact(v.z), gelu_exact(v.w));
}

// ---------------- Kernel 0: init qp + qkbuf accumulators (ws is poisoned 0xAA) ----------------
// kp needs no init: conv1x1 head-1 blocks write every kp element directly.
__global__ __launch_bounds__(256) void init_kernel(float4* __restrict__ qp, float4* __restrict__ qkb)
{
    int bid = blockIdx.x;
    if (bid < 2048) {
        size_t i = (size_t)bid * 256 + threadIdx.x;       // 524288 float4 = qp
        qp[i] = make_float4(0.f, 0.f, 0.f, 0.f);
    } else {
        size_t i = (size_t)(bid - 2048) * 256 + threadIdx.x;  // 32768 float4 = qkbuf
        qkb[i] = make_float4(0.f, 0.f, 0.f, 0.f);
    }
}

// ---------------- Kernel 1: x1 branch (identity + 3 depthwise convs) + GELU ----------------
__global__ __launch_bounds__(256) void part1_kernel(
    const float* __restrict__ x,
    const float* __restrict__ w_hw, const float* __restrict__ b_hw,
    const float* __restrict__ w_w,  const float* __restrict__ b_w,
    const float* __restrict__ w_h,  const float* __restrict__ b_h,
    float* __restrict__ out)
{
    int bc = blockIdx.x;            // b*128 + c
    int b  = bc >> 7;
    int c  = bc & 127;
    const float4* xp4 = (const float4*)(x   + (size_t)(b * kC + c) * kHW);
    float4*       op4 = (float4*)      (out + (size_t)(b * kC + c) * kHW);
    int tid = threadIdx.x;

    if (c < kNID) {
        for (int q = tid; q < 1024; q += 256)
            op4[q] = gelu4(xp4[q]);
    } else if (c < kNID + kGC) {           // 3x3 dwconv, pad 1
        int g = c - kNID;
        float wv[9];
        #pragma unroll
        for (int j = 0; j < 9; ++j) wv[j] = w_hw[g * 9 + j];
        float bias = b_hw[g];
        for (int q = tid; q < 1024; q += 256) {
            int h = q >> 4, wq = q & 15;
            float ax = bias, ay = bias, az = bias, aw = bias;
            #pragma unroll
            for (int dy = -1; dy <= 1; ++dy) {
                int rr = h + dy;
                if ((unsigned)rr >= 64u) continue;
                int base = rr * 16;
                float  l  = (wq > 0)  ? xp4[base + wq - 1].w : 0.f;
                float4 Bv = xp4[base + wq];
                float  r  = (wq < 15) ? xp4[base + wq + 1].x : 0.f;
                float w0 = wv[(dy + 1) * 3 + 0];
                float w1 = wv[(dy + 1) * 3 + 1];
                float w2 = wv[(dy + 1) * 3 + 2];
                ax += w0 * l    + w1 * Bv.x + w2 * Bv.y;
                ay += w0 * Bv.x + w1 * Bv.y + w2 * Bv.z;
                az += w0 * Bv.y + w1 * Bv.z + w2 * Bv.w;
                aw += w0 * Bv.z + w1 * Bv.w + w2 * r;
            }
            op4[q] = make_float4(gelu_exact(ax), gelu_exact(ay), gelu_exact(az), gelu_exact(aw));
        }
    } else if (c < kNID + 2 * kGC) {       // 1x11 dwconv, pad (0,5)
        int g = c - (kNID + kGC);
        float wv[11];
        #pragma unroll
        for (int j = 0; j < 11; ++j) wv[j] = w_w[g * 11 + j];
        float bias = b_w[g];
        for (int q = tid; q < 1024; q += 256) {
            int h = q >> 4, wq = q & 15;
            int base = h * 16;
            float f[20];
            #pragma unroll
            for (int m = 0; m < 5; ++m) {
                int qq = wq + m - 2;
                float4 v;
                if ((unsigned)qq < 16u) v = xp4[base + qq];
                else                    v = make_float4(0.f, 0.f, 0.f, 0.f);
                f[4 * m + 0] = v.x; f[4 * m + 1] = v.y;
                f[4 * m + 2] = v.z; f[4 * m + 3] = v.w;
            }
            float a0 = bias, a1 = bias, a2 = bias, a3 = bias;
            #pragma unroll
            for (int m = 0; m < 11; ++m) {
                float w = wv[m];
                a0 += w * f[m + 3];
                a1 += w * f[m + 4];
                a2 += w * f[m + 5];
                a3 += w * f[m + 6];
            }
            op4[q] = make_float4(gelu_exact(a0), gelu_exact(a1), gelu_exact(a2), gelu_exact(a3));
        }
    } else {                               // 11x1 dwconv, pad (5,0)
        int g = c - (kNID + 2 * kGC);
        float wv[11];
        #pragma unroll
        for (int j = 0; j < 11; ++j) wv[j] = w_h[g * 11 + j];
        float bias = b_h[g];
        for (int q = tid; q < 1024; q += 256) {
            int h = q >> 4, wq = q & 15;
            float a0 = bias, a1 = bias, a2 = bias, a3 = bias;
            #pragma unroll
            for (int m = 0; m < 11; ++m) {
                int rr = h + m - 5;
                if ((unsigned)rr < 64u) {
                    float4 v = xp4[rr * 16 + wq];
                    float w = wv[m];
                    a0 += w * v.x; a1 += w * v.y; a2 += w * v.z; a3 += w * v.w;
                }
            }
            op4[q] = make_float4(gelu_exact(a0), gelu_exact(a1), gelu_exact(a2), gelu_exact(a3));
        }
    }
}

// ---------------- Kernel 2: 1x1 conv GEMM + GELU + pooling ----------------
// Grid: (16 pixel-blocks of 256 px = 4 image rows, 4 heads, B). Block 256.
// Tile: o=64 x p=256, per-thread 8x8 acc -> 64 FMA per 4 ds_read_b128.
// LDS 40KB; launch_bounds(256,3) gives the allocator ~170 VGPR headroom so the
// 64-reg accumulator stays in VGPRs (r2's (256,4) pin at 64 VGPR forced
// accumulator shuffling and was SLOWER despite higher occupancy).
__global__ __launch_bounds__(256, 3) void conv1x1_kernel(
    const float* __restrict__ x,
    const float* __restrict__ w_qkvl, const float* __restrict__ b_qkvl,
    float* __restrict__ qp, float* __restrict__ kp,
    float* __restrict__ out)
{
    __shared__ float Ws[32][64];     // [k][o]
    __shared__ float Xs[32 * 256];   // row k at k*256; reused as Ps[64][4][32] in epilogue
    int pb   = blockIdx.x;           // 0..15
    int p0   = pb * 256;
    int head = blockIdx.y;
    int o0   = head * 64;
    int b    = blockIdx.z;
    int t    = threadIdx.x;
    int og   = t >> 5;               // 0..7 : o = og*8 + i
    int tp   = t & 31;               // 0..31: p = tp*8 + j

    float acc[8][8] = {};
    for (int kc = 0; kc < 4; ++kc) {
        // stage W: 32k x 64o (each task = 4 consecutive k for one o)
        #pragma unroll
        for (int r = 0; r < 2; ++r) {
            int g = t + r * 256;                 // 0..511
            int o = g & 63, kq = g >> 6;         // kq 0..7
            float4 w4 = *(const float4*)&w_qkvl[(size_t)(o0 + o) * 128 + kc * 32 + kq * 4];
            Ws[kq * 4 + 0][o] = w4.x;
            Ws[kq * 4 + 1][o] = w4.y;
            Ws[kq * 4 + 2][o] = w4.z;
            Ws[kq * 4 + 3][o] = w4.w;
        }
        // stage X: 32k x 256p float4, even/odd chunk deinterleave
        #pragma unroll
        for (int r = 0; r < 8; ++r) {
            int g = t + r * 256;                 // 0..2047
            int k = g >> 6, cch = g & 63;        // cch = orig float4 chunk
            int cph = (cch >> 1) + (cch & 1) * 32;
            *(float4*)&Xs[k * 256 + cph * 4] =
                *(const float4*)&x[(size_t)(b * kC + 128 + kc * 32 + k) * kHW + p0 + cch * 4];
        }
        __syncthreads();
        #pragma unroll 2
        for (int k = 0; k < 32; ++k) {
            const float* xrow = &Xs[k * 256];
            float4 wa = *(const float4*)&Ws[k][og * 8];
            float4 wb = *(const float4*)&Ws[k][og * 8 + 4];
            float4 xa = *(const float4*)&xrow[tp * 4];         // pixels tp*8..+3
            float4 xb = *(const float4*)&xrow[128 + tp * 4];   // pixels tp*8+4..+7
            float w8[8] = {wa.x, wa.y, wa.z, wa.w, wb.x, wb.y, wb.z, wb.w};
            float x8[8] = {xa.x, xa.y, xa.z, xa.w, xb.x, xb.y, xb.z, xb.w};
            #pragma unroll
            for (int i = 0; i < 8; ++i)
                #pragma unroll
                for (int j = 0; j < 8; ++j)
                    acc[i][j] += w8[i] * x8[j];
        }
        __syncthreads();
    }

    if (head < 2) {
        // per-thread horizontal pooling in registers, then tiny LDS combine.
        float* Ps = &Xs[0];            // [o][r][m] : o*128 + r*32 + m
        int r  = tp >> 3;              // image row within tile (0..3)
        int m0 = (tp & 7) * 4;         // first pool cell
        #pragma unroll
        for (int i = 0; i < 8; ++i) {
            int o = og * 8 + i;
            float bias = b_qkvl[o0 + o];
            float y[8];
            #pragma unroll
            for (int j = 0; j < 8; ++j) y[j] = gelu_exact(acc[i][j] + bias);
            float s[4];
            if (head == 0) {           // 3-wide sums (pad-1 left), stride 2
                float left = __shfl_up(y[7], 1);
                if ((tp & 7) == 0) left = 0.0f;
                s[0] = left + y[0] + y[1];
                s[1] = y[1] + y[2] + y[3];
                s[2] = y[3] + y[4] + y[5];
                s[3] = y[5] + y[6] + y[7];
            } else {                   // 2-wide max, stride 2
                s[0] = fmaxf(y[0], y[1]);
                s[1] = fmaxf(y[2], y[3]);
                s[2] = fmaxf(y[4], y[5]);
                s[3] = fmaxf(y[6], y[7]);
            }
            *(float4*)&Ps[o * 128 + r * 32 + m0] = *(float4*)s;
        }
        __syncthreads();
        if (head == 0) {
            bool last = (pb == 15);
            for (int e = t; e < 2048; e += 256) {
                int o = e >> 5, m = e & 31;
                const float* P = &Ps[o * 128 + m];
                float pv0 = P[0], pv1 = P[32], pv2 = P[64], pv3 = P[96];
                float* dst = &qp[(((size_t)(b * kC4 + o)) << 10) + (2 * pb) * 32 + m];
                dst[32] = (pv1 + pv2 + pv3) * (1.0f / 9.0f);          // pool row 2pb+1: fully local
                atomicAdd(dst, (pv0 + pv1) * (1.0f / 9.0f));          // pool row 2pb (rows r0,r1)
                if (!last) atomicAdd(dst + 64, pv3 * (1.0f / 9.0f));  // row r3 -> pool row 2pb+2
            }
        } else {
            for (int e = t; e < 2048; e += 256) {
                int o = e >> 5, m = e & 31;
                const float* P = &Ps[o * 128 + m];
                float* dst = &kp[(((size_t)(b * kC4 + o)) << 10) + (2 * pb) * 32 + m];
                dst[0]  = fmaxf(P[0],  P[32]);
                dst[32] = fmaxf(P[64], P[96]);
            }
        }
    } else {
        // v -> out ch 192..255 (temp storage), lfeat -> out ch 128..191
        int cbase = (head == 2) ? 192 : 128;
        #pragma unroll
        for (int i = 0; i < 8; ++i) {
            int o = og * 8 + i;
            float bias = b_qkvl[o0 + o];
            float4 ya = make_float4(gelu_exact(acc[i][0] + bias), gelu_exact(acc[i][1] + bias),
                                    gelu_exact(acc[i][2] + bias), gelu_exact(acc[i][3] + bias));
            float4 yb = make_float4(gelu_exact(acc[i][4] + bias), gelu_exact(acc[i][5] + bias),
                                    gelu_exact(acc[i][6] + bias), gelu_exact(acc[i][7] + bias));
            float* dst = &out[(size_t)(b * kC + cbase + o) * kHW + p0 + tp * 8];
            *(float4*)dst       = ya;
            *(float4*)(dst + 4) = yb;
        }
    }
}

// ---------------- Kernel 3a: partial qk[c][d] += sum_{n-chunk} qf[c][n] kf[d][n] ----------------
// Grid (8 n-chunks of 128, B) = 256 blocks (full CU coverage vs old 128).
// Both operands staged TRANSPOSED [n][ch] so inner loop = 2 b128 per 16 FMA.
__global__ __launch_bounds__(256) void qk_partial_kernel(
    const float* __restrict__ qp, const float* __restrict__ kp,
    float* __restrict__ qkb)
{
    __shared__ float qsT[128][65];   // [n][c] 33.3 KB
    __shared__ float ksT[128][65];   // [n][d] 33.3 KB
    int nb = blockIdx.x;             // n-chunk
    int b  = blockIdx.y;
    int t  = threadIdx.x;
    int tc = t & 15;                 // c-tile: c = tc*4+i
    int td = t >> 4;                 // d-tile: d = td*4+j

    #pragma unroll
    for (int r = 0; r < 8; ++r) {
        int g = t + r * 256;         // 0..2047
        int ch = g >> 5, n4 = g & 31;
        float4 q4 = *(const float4*)&qp[(size_t)(b * 64 + ch) * 1024 + nb * 128 + n4 * 4];
        qsT[n4 * 4 + 0][ch] = q4.x;
        qsT[n4 * 4 + 1][ch] = q4.y;
        qsT[n4 * 4 + 2][ch] = q4.z;
        qsT[n4 * 4 + 3][ch] = q4.w;
        float4 k4 = *(const float4*)&kp[(size_t)(b * 64 + ch) * 1024 + nb * 128 + n4 * 4];
        ksT[n4 * 4 + 0][ch] = k4.x;
        ksT[n4 * 4 + 1][ch] = k4.y;
        ksT[n4 * 4 + 2][ch] = k4.z;
        ksT[n4 * 4 + 3][ch] = k4.w;
    }
    __syncthreads();

    float acc[4][4] = {};
    #pragma unroll 4
    for (int n = 0; n < 128; ++n) {
        float4 q4 = *(const float4*)&qsT[n][tc * 4];
        float4 k4 = *(const float4*)&ksT[n][td * 4];
        float qa[4] = {q4.x, q4.y, q4.z, q4.w};
        float ka[4] = {k4.x, k4.y, k4.z, k4.w};
        #pragma unroll
        for (int i = 0; i < 4; ++i)
            #pragma unroll
            for (int j = 0; j < 4; ++j)
                acc[i][j] += qa[i] * ka[j];
    }
    #pragma unroll
    for (int i = 0; i < 4; ++i)
        #pragma unroll
        for (int j = 0; j < 4; ++j)
            atomicAdd(&qkb[((size_t)b * 64 + tc * 4 + i) * 64 + td * 4 + j], acc[i][j]);
}

// ---------------- Kernel 3b: softmax over c per (b, d) ----------------
__global__ __launch_bounds__(256) void softmax_kernel(
    const float* __restrict__ qkb, float* __restrict__ attn)
{
    __shared__ float qk_s[64][65];
    __shared__ float mxs[64], sms[64];
    int b = blockIdx.x;
    int t = threadIdx.x;
    #pragma unroll
    for (int r = 0; r < 16; ++r) {
        int g = t + r * 256;
        qk_s[g >> 6][g & 63] = qkb[(size_t)b * 4096 + g];
    }
    __syncthreads();
    if (t < 64) {
        float m = -1e30f;
        #pragma unroll 4
        for (int cc = 0; cc < 64; ++cc) m = fmaxf(m, qk_s[cc][t]);
        float s = 0.f;
        #pragma unroll 4
        for (int cc = 0; cc < 64; ++cc) s += expf(qk_s[cc][t] - m);
        mxs[t] = m;
        sms[t] = 1.0f / s;
    }
    __syncthreads();
    #pragma unroll
    for (int r = 0; r < 16; ++r) {
        int g = t + r * 256;
        int c = g >> 6, d = g & 63;
        attn[(size_t)b * 4096 + g] = expf(qk_s[c][d] - mxs[d]) * sms[d];
    }
}

// ---------------- Kernel 4: out[b,192+d,m] = sum_c attn[b,c,d] * v[b,c,m] ----------------
// ~BW-bound (134 MB): chunked v-loads with static indexing, at via LDS broadcast.
__global__ __launch_bounds__(256) void out2_kernel(
    const float* __restrict__ attn, float* __restrict__ out)
{
    __shared__ float at[64][64];   // [c][d]
    int b = blockIdx.y;
    int t = threadIdx.x;
    #pragma unroll
    for (int r = 0; r < 4; ++r) {
        int g = t + r * 256;       // 0..1023 float4 tasks
        *(float4*)&at[g >> 4][(g & 15) * 4] = *(const float4*)&attn[(size_t)b * 4096 + g * 4];
    }
    __syncthreads();
    int m = blockIdx.x * 256 + t;
    float* vcol = out + (size_t)(b * kC + 192) * kHW + m;   // stride kHW per channel
    float acc[64] = {};
    for (int c8 = 0; c8 < 8; ++c8) {
        float v[8];
        #pragma unroll
        for (int j = 0; j < 8; ++j) v[j] = vcol[(size_t)(c8 * 8 + j) * kHW];
        #pragma unroll
        for (int j = 0; j < 8; ++j) {
            float vv = v[j];
            const float* arow = &at[c8 * 8 + j][0];
            #pragma unroll
            for (int d4 = 0; d4 < 16; ++d4) {
                float4 a = *(const float4*)&arow[d4 * 4];
                acc[d4 * 4 + 0] += a.x * vv;
                acc[d4 * 4 + 1] += a.y * vv;
                acc[d4 * 4 + 2] += a.z * vv;
                acc[d4 * 4 + 3] += a.w * vv;
            }
        }
    }
    #pragma unroll
    for (int d = 0; d < 64; ++d)
        vcol[(size_t)d * kHW] = acc[d];
}

extern "C" void kernel_launch(void* const* d_in, const int* in_sizes, int n_in,
                              void* d_out, int out_size, void* d_ws, size_t ws_size,
                              hipStream_t stream)
{
    const float* x      = (const float*)d_in[0];
    const float* w_hw   = (const float*)d_in[1];
    const float* b_hw   = (const float*)d_in[2];
    const float* w_w    = (const float*)d_in[3];
    const float* b_w    = (const float*)d_in[4];
    const float* w_h    = (const float*)d_in[5];
    const float* b_h    = (const float*)d_in[6];
    const float* w_qkvl = (const float*)d_in[7];
    const float* b_qkvl = (const float*)d_in[8];
    float* out = (float*)d_out;

    // Workspace layout (~17.8 MB): qp fp32 | kp fp32 | attn fp32 | qkbuf fp32
    char* w = (char*)d_ws;
    float* qp   = (float*)w;  w += (size_t)kB * kC4 * 1024 * 4;   // 8.39 MB
    float* kp   = (float*)w;  w += (size_t)kB * kC4 * 1024 * 4;   // 8.39 MB
    float* attn = (float*)w;  w += (size_t)kB * kC4 * kC4 * 4;    // 0.52 MB
    float* qkb  = (float*)w;  w += (size_t)kB * kC4 * kC4 * 4;    // 0.52 MB

    init_kernel<<<dim3(2176), 256, 0, stream>>>((float4*)qp, (float4*)qkb);
    part1_kernel<<<dim3(kB * 128), 256, 0, stream>>>(x, w_hw, b_hw, w_w, b_w, w_h, b_h, out);
    conv1x1_kernel<<<dim3(16, 4, kB), 256, 0, stream>>>(x, w_qkvl, b_qkvl, qp, kp, out);
    qk_partial_kernel<<<dim3(8, kB), 256, 0, stream>>>(qp, kp, qkb);
    softmax_kernel<<<dim3(kB), 256, 0, stream>>>(qkb, attn);
    out2_kernel<<<dim3(16, kB), 256, 0, stream>>>(attn, out);
}

// Round 5
// 426.633 us; speedup vs baseline: 1.7621x; 1.0591x over previous
//
#include <hip/hip_runtime.h>
#include <hip/hip_bf16.h>

constexpr int kB   = 32;
constexpr int kC   = 256;
constexpr int kHW  = 4096;   // 64*64
constexpr int kC4  = 64;
constexpr int kGC  = 16;
constexpr int kNID = 80;     // 128 - 3*16

__device__ __forceinline__ float gelu_exact(float x) {
    return 0.5f * x * (1.0f + erff(x * 0.70710678118654752440f));
}

__device__ __forceinline__ float4 gelu4(float4 v) {
    return make_float4(gelu_exact(v.x), gelu_exact(v.y), gelu_exact(v.z), gelu_exact(v.w));
}

// ---------------- Kernel 0: init qp + qkbuf accumulators (ws is poisoned 0xAA) ----------------
// kp needs no init: conv1x1 head-1 blocks write every kp element directly.
// (init kernel, NOT hipMemsetAsync: graph-capture-safe, proven r0-r3.)
__global__ __launch_bounds__(256) void init_kernel(float4* __restrict__ qp, float4* __restrict__ qkb)
{
    int bid = blockIdx.x;
    if (bid < 2048) {
        size_t i = (size_t)bid * 256 + threadIdx.x;           // 524288 float4 = qp
        qp[i] = make_float4(0.f, 0.f, 0.f, 0.f);
    } else {
        size_t i = (size_t)(bid - 2048) * 256 + threadIdx.x;  // 32768 float4 = qkbuf
        qkb[i] = make_float4(0.f, 0.f, 0.f, 0.f);
    }
}

// ---------------- Kernel W: transpose w_qkvl [o][k] -> wT [k][o] (128 KB) ----------------
// Enables wave-uniform SCALAR loads of W in conv1x1 (takes W off the LDS pipe).
__global__ __launch_bounds__(256) void wt_kernel(
    const float* __restrict__ w_qkvl, float* __restrict__ wT)
{
    int k0 = blockIdx.x * 8;       // 16 blocks x 8 k
    int o  = threadIdx.x;
    #pragma unroll
    for (int r = 0; r < 8; ++r)
        wT[(size_t)(k0 + r) * 256 + o] = w_qkvl[(size_t)o * 128 + k0 + r];
}

// ---------------- Kernel 1: x1 branch (identity + 3 depthwise convs) + GELU ----------------
__global__ __launch_bounds__(256) void part1_kernel(
    const float* __restrict__ x,
    const float* __restrict__ w_hw, const float* __restrict__ b_hw,
    const float* __restrict__ w_w,  const float* __restrict__ b_w,
    const float* __restrict__ w_h,  const float* __restrict__ b_h,
    float* __restrict__ out)
{
    int bc = blockIdx.x;            // b*128 + c
    int b  = bc >> 7;
    int c  = bc & 127;
    const float4* xp4 = (const float4*)(x   + (size_t)(b * kC + c) * kHW);
    float4*       op4 = (float4*)      (out + (size_t)(b * kC + c) * kHW);
    int tid = threadIdx.x;

    if (c < kNID) {
        for (int q = tid; q < 1024; q += 256)
            op4[q] = gelu4(xp4[q]);
    } else if (c < kNID + kGC) {           // 3x3 dwconv, pad 1
        int g = c - kNID;
        float wv[9];
        #pragma unroll
        for (int j = 0; j < 9; ++j) wv[j] = w_hw[g * 9 + j];
        float bias = b_hw[g];
        for (int q = tid; q < 1024; q += 256) {
            int h = q >> 4, wq = q & 15;
            float ax = bias, ay = bias, az = bias, aw = bias;
            #pragma unroll
            for (int dy = -1; dy <= 1; ++dy) {
                int rr = h + dy;
                if ((unsigned)rr >= 64u) continue;
                int base = rr * 16;
                float  l  = (wq > 0)  ? xp4[base + wq - 1].w : 0.f;
                float4 Bv = xp4[base + wq];
                float  r  = (wq < 15) ? xp4[base + wq + 1].x : 0.f;
                float w0 = wv[(dy + 1) * 3 + 0];
                float w1 = wv[(dy + 1) * 3 + 1];
                float w2 = wv[(dy + 1) * 3 + 2];
                ax += w0 * l    + w1 * Bv.x + w2 * Bv.y;
                ay += w0 * Bv.x + w1 * Bv.y + w2 * Bv.z;
                az += w0 * Bv.y + w1 * Bv.z + w2 * Bv.w;
                aw += w0 * Bv.z + w1 * Bv.w + w2 * r;
            }
            op4[q] = make_float4(gelu_exact(ax), gelu_exact(ay), gelu_exact(az), gelu_exact(aw));
        }
    } else if (c < kNID + 2 * kGC) {       // 1x11 dwconv, pad (0,5)
        int g = c - (kNID + kGC);
        float wv[11];
        #pragma unroll
        for (int j = 0; j < 11; ++j) wv[j] = w_w[g * 11 + j];
        float bias = b_w[g];
        for (int q = tid; q < 1024; q += 256) {
            int h = q >> 4, wq = q & 15;
            int base = h * 16;
            float f[20];
            #pragma unroll
            for (int m = 0; m < 5; ++m) {
                int qq = wq + m - 2;
                float4 v;
                if ((unsigned)qq < 16u) v = xp4[base + qq];
                else                    v = make_float4(0.f, 0.f, 0.f, 0.f);
                f[4 * m + 0] = v.x; f[4 * m + 1] = v.y;
                f[4 * m + 2] = v.z; f[4 * m + 3] = v.w;
            }
            float a0 = bias, a1 = bias, a2 = bias, a3 = bias;
            #pragma unroll
            for (int m = 0; m < 11; ++m) {
                float w = wv[m];
                a0 += w * f[m + 3];
                a1 += w * f[m + 4];
                a2 += w * f[m + 5];
                a3 += w * f[m + 6];
            }
            op4[q] = make_float4(gelu_exact(a0), gelu_exact(a1), gelu_exact(a2), gelu_exact(a3));
        }
    } else {                               // 11x1 dwconv, pad (5,0)
        int g = c - (kNID + 2 * kGC);
        float wv[11];
        #pragma unroll
        for (int j = 0; j < 11; ++j) wv[j] = w_h[g * 11 + j];
        float bias = b_h[g];
        for (int q = tid; q < 1024; q += 256) {
            int h = q >> 4, wq = q & 15;
            float a0 = bias, a1 = bias, a2 = bias, a3 = bias;
            #pragma unroll
            for (int m = 0; m < 11; ++m) {
                int rr = h + m - 5;
                if ((unsigned)rr < 64u) {
                    float4 v = xp4[rr * 16 + wq];
                    float w = wv[m];
                    a0 += w * v.x; a1 += w * v.y; a2 += w * v.z; a3 += w * v.w;
                }
            }
            op4[q] = make_float4(gelu_exact(a0), gelu_exact(a1), gelu_exact(a2), gelu_exact(a3));
        }
    }
}

// ---------------- Kernel 2: 1x1 conv GEMM + GELU + pooling ----------------
// Grid: (16 px-blocks of 256 = 4 rows, 4 heads, B). Block 256 = 4 waves.
// Each WAVE owns a wave-uniform 16-o strip -> W comes in via SCALAR loads (SMEM
// pipe, v_fmac v,s,v), X via ONE conflict-free ds_read_b128 per k per lane.
// LDS demand per k-step: ~12 cyc vs 128 VALU-cyc -> VALU-bound (r3: 4 b128 -> 66%).
// acc[16 o][4 px]; LDS = Xs 32k x 256px = 32 KB (reused as Ps in epilogue).
__global__ __launch_bounds__(256) void conv1x1_kernel(
    const float* __restrict__ x,
    const float* __restrict__ wT, const float* __restrict__ b_qkvl,
    float* __restrict__ qp, float* __restrict__ kp,
    float* __restrict__ out)
{
    __shared__ float Xs[32 * 256];   // row k at k*256; reused as Ps[64][4][32] in epilogue
    int pb   = blockIdx.x;           // 0..15
    int p0   = pb * 256;
    int head = blockIdx.y;
    int b    = blockIdx.z;
    int t    = threadIdx.x;
    int lane = t & 63;
    int wvid = __builtin_amdgcn_readfirstlane(t >> 6);   // wave id 0..3, SGPR
    int ow   = head * 64 + wvid * 16;                    // wave's first output ch (uniform)

    float acc[16][4] = {};
    for (int kc = 0; kc < 4; ++kc) {
        // stage X: 32k x 256p float4, fully coalesced, linear layout
        #pragma unroll
        for (int r = 0; r < 8; ++r) {
            int g = t + r * 256;                 // 0..2047
            int k = g >> 6, cch = g & 63;
            *(float4*)&Xs[k * 256 + cch * 4] =
                *(const float4*)&x[(size_t)(b * kC + 128 + kc * 32 + k) * kHW + p0 + cch * 4];
        }
        __syncthreads();
        #pragma unroll 4
        for (int k = 0; k < 32; ++k) {
            const float* wr = wT + (size_t)(kc * 32 + k) * 256 + ow;   // uniform -> s_load
            float4 w0 = *(const float4*)&wr[0];
            float4 w1 = *(const float4*)&wr[4];
            float4 w2 = *(const float4*)&wr[8];
            float4 w3 = *(const float4*)&wr[12];
            float4 xv = *(const float4*)&Xs[k * 256 + lane * 4];       // px 4*lane..+3
            float wv[16] = {w0.x, w0.y, w0.z, w0.w, w1.x, w1.y, w1.z, w1.w,
                            w2.x, w2.y, w2.z, w2.w, w3.x, w3.y, w3.z, w3.w};
            float xa[4] = {xv.x, xv.y, xv.z, xv.w};
            #pragma unroll
            for (int i = 0; i < 16; ++i)
                #pragma unroll
                for (int j = 0; j < 4; ++j)
                    acc[i][j] += wv[i] * xa[j];
        }
        __syncthreads();
    }

    if (head < 2) {
        // per-lane horizontal pooling in registers, then LDS combine (r3-proven).
        float* Ps = &Xs[0];            // [o][r][m] : o*128 + r*32 + m  (32 KB)
        int r  = lane >> 4;            // image row within tile (0..3), 16 lanes/row
        int m0 = 2 * (lane & 15);      // first of 2 pool cells (px_in_row = 4*(lane&15))
        #pragma unroll
        for (int i = 0; i < 16; ++i) {
            int o = wvid * 16 + i;
            float bias = b_qkvl[ow + i];
            float y0 = gelu_exact(acc[i][0] + bias);
            float y1 = gelu_exact(acc[i][1] + bias);
            float y2 = gelu_exact(acc[i][2] + bias);
            float y3 = gelu_exact(acc[i][3] + bias);
            float s0, s1;
            if (head == 0) {           // 3-wide sums (pad-1 left), stride 2
                float left = __shfl_up(y3, 1);
                if ((lane & 15) == 0) left = 0.0f;
                s0 = left + y0 + y1;
                s1 = y1 + y2 + y3;
            } else {                   // 2-wide max, stride 2
                s0 = fmaxf(y0, y1);
                s1 = fmaxf(y2, y3);
            }
            Ps[o * 128 + r * 32 + m0]     = s0;
            Ps[o * 128 + r * 32 + m0 + 1] = s1;
        }
        __syncthreads();
        if (head == 0) {
            bool last = (pb == 15);
            for (int e = t; e < 2048; e += 256) {
                int o = e >> 5, m = e & 31;
                const float* P = &Ps[o * 128 + m];
                float pv0 = P[0], pv1 = P[32], pv2 = P[64], pv3 = P[96];
                float* dst = &qp[(((size_t)(b * kC4 + o)) << 10) + (2 * pb) * 32 + m];
                dst[32] = (pv1 + pv2 + pv3) * (1.0f / 9.0f);          // pool row 2pb+1: fully local
                atomicAdd(dst, (pv0 + pv1) * (1.0f / 9.0f));          // pool row 2pb
                if (!last) atomicAdd(dst + 64, pv3 * (1.0f / 9.0f));  // row r3 -> pool row 2pb+2
            }
        } else {
            for (int e = t; e < 2048; e += 256) {
                int o = e >> 5, m = e & 31;
                const float* P = &Ps[o * 128 + m];
                float* dst = &kp[(((size_t)(b * kC4 + o)) << 10) + (2 * pb) * 32 + m];
                dst[0]  = fmaxf(P[0],  P[32]);
                dst[32] = fmaxf(P[64], P[96]);
            }
        }
    } else {
        // v (head2: o 128..191 -> out ch 192..255), lfeat (head3: o 192..255 -> out ch 128..191)
        #pragma unroll
        for (int i = 0; i < 16; ++i) {
            int og  = ow + i;
            int och = (head == 2) ? (og + 64) : (og - 64);
            float bias = b_qkvl[og];
            float4 y = make_float4(gelu_exact(acc[i][0] + bias), gelu_exact(acc[i][1] + bias),
                                   gelu_exact(acc[i][2] + bias), gelu_exact(acc[i][3] + bias));
            *(float4*)&out[(size_t)(b * kC + och) * kHW + p0 + lane * 4] = y;
        }
    }
}

// ---------------- Kernel 3a: partial qk[c][d] += sum_{n-chunk} qf[c][n] kf[d][n] ----------------
__global__ __launch_bounds__(256) void qk_partial_kernel(
    const float* __restrict__ qp, const float* __restrict__ kp,
    float* __restrict__ qkb)
{
    __shared__ float qsT[128][65];   // [n][c] 33.3 KB
    __shared__ float ksT[128][65];   // [n][d] 33.3 KB
    int nb = blockIdx.x;             // n-chunk
    int b  = blockIdx.y;
    int t  = threadIdx.x;
    int tc = t & 15;                 // c-tile: c = tc*4+i
    int td = t >> 4;                 // d-tile: d = td*4+j

    #pragma unroll
    for (int r = 0; r < 8; ++r) {
        int g = t + r * 256;         // 0..2047
        int ch = g >> 5, n4 = g & 31;
        float4 q4 = *(const float4*)&qp[(size_t)(b * 64 + ch) * 1024 + nb * 128 + n4 * 4];
        qsT[n4 * 4 + 0][ch] = q4.x;
        qsT[n4 * 4 + 1][ch] = q4.y;
        qsT[n4 * 4 + 2][ch] = q4.z;
        qsT[n4 * 4 + 3][ch] = q4.w;
        float4 k4 = *(const float4*)&kp[(size_t)(b * 64 + ch) * 1024 + nb * 128 + n4 * 4];
        ksT[n4 * 4 + 0][ch] = k4.x;
        ksT[n4 * 4 + 1][ch] = k4.y;
        ksT[n4 * 4 + 2][ch] = k4.z;
        ksT[n4 * 4 + 3][ch] = k4.w;
    }
    __syncthreads();

    float acc[4][4] = {};
    #pragma unroll 4
    for (int n = 0; n < 128; ++n) {
        float4 q4 = *(const float4*)&qsT[n][tc * 4];
        float4 k4 = *(const float4*)&ksT[n][td * 4];
        float qa[4] = {q4.x, q4.y, q4.z, q4.w};
        float ka[4] = {k4.x, k4.y, k4.z, k4.w};
        #pragma unroll
        for (int i = 0; i < 4; ++i)
            #pragma unroll
            for (int j = 0; j < 4; ++j)
                acc[i][j] += qa[i] * ka[j];
    }
    #pragma unroll
    for (int i = 0; i < 4; ++i)
        #pragma unroll
        for (int j = 0; j < 4; ++j)
            atomicAdd(&qkb[((size_t)b * 64 + tc * 4 + i) * 64 + td * 4 + j], acc[i][j]);
}

// ---------------- Kernel 3b: softmax over c per (b, d) ----------------
__global__ __launch_bounds__(256) void softmax_kernel(
    const float* __restrict__ qkb, float* __restrict__ attn)
{
    __shared__ float qk_s[64][65];
    __shared__ float mxs[64], sms[64];
    int b = blockIdx.x;
    int t = threadIdx.x;
    #pragma unroll
    for (int r = 0; r < 16; ++r) {
        int g = t + r * 256;
        qk_s[g >> 6][g & 63] = qkb[(size_t)b * 4096 + g];
    }
    __syncthreads();
    if (t < 64) {
        float m = -1e30f;
        #pragma unroll 4
        for (int cc = 0; cc < 64; ++cc) m = fmaxf(m, qk_s[cc][t]);
        float s = 0.f;
        #pragma unroll 4
        for (int cc = 0; cc < 64; ++cc) s += expf(qk_s[cc][t] - m);
        mxs[t] = m;
        sms[t] = 1.0f / s;
    }
    __syncthreads();
    #pragma unroll
    for (int r = 0; r < 16; ++r) {
        int g = t + r * 256;
        int c = g >> 6, d = g & 63;
        attn[(size_t)b * 4096 + g] = expf(qk_s[c][d] - mxs[d]) * sms[d];
    }
}

// ---------------- Kernel 4: out[b,192+d,m] = sum_c attn[b,c,d] * v[b,c,m] ----------------
// attn rows are block-uniform -> SCALAR loads (no LDS at all). v loads coalesced.
__global__ __launch_bounds__(256) void out2_kernel(
    const float* __restrict__ attn, float* __restrict__ out)
{
    int b = blockIdx.y;
    int t = threadIdx.x;
    int m = blockIdx.x * 256 + t;
    float* vcol = out + (size_t)(b * kC + 192) * kHW + m;   // stride kHW per channel
    const float* ar = attn + (size_t)b * 4096;              // uniform rows -> s_load
    float acc[64] = {};
    #pragma unroll 2
    for (int c = 0; c < 64; ++c) {
        float vv = vcol[(size_t)c * kHW];
        const float* arow = ar + c * 64;
        #pragma unroll
        for (int d = 0; d < 64; ++d)
            acc[d] += arow[d] * vv;
    }
    #pragma unroll
    for (int d = 0; d < 64; ++d)
        vcol[(size_t)d * kHW] = acc[d];
}

extern "C" void kernel_launch(void* const* d_in, const int* in_sizes, int n_in,
                              void* d_out, int out_size, void* d_ws, size_t ws_size,
                              hipStream_t stream)
{
    const float* x      = (const float*)d_in[0];
    const float* w_hw   = (const float*)d_in[1];
    const float* b_hw   = (const float*)d_in[2];
    const float* w_w    = (const float*)d_in[3];
    const float* b_w    = (const float*)d_in[4];
    const float* w_h    = (const float*)d_in[5];
    const float* b_h    = (const float*)d_in[6];
    const float* w_qkvl = (const float*)d_in[7];
    const float* b_qkvl = (const float*)d_in[8];
    float* out = (float*)d_out;

    // Workspace (17.83 MB, identical footprint to r3): qp | kp | attn | qkb.
    // wT (128 KB) ALIASES attn: wT is consumed by conv1x1, attn is first
    // written by softmax_kernel (two launches later) -> disjoint lifetimes.
    char* w = (char*)d_ws;
    float* qp   = (float*)w;  w += (size_t)kB * kC4 * 1024 * 4;   // 8.39 MB (atomic-accum)
    float* kp   = (float*)w;  w += (size_t)kB * kC4 * 1024 * 4;   // 8.39 MB (fully written)
    float* attn = (float*)w;  w += (size_t)kB * kC4 * kC4 * 4;    // 0.52 MB
    float* qkb  = (float*)w;  w += (size_t)kB * kC4 * kC4 * 4;    // 0.52 MB (atomic-accum)
    float* wT   = attn;                                           // 0.13 MB, lifetime-disjoint

    init_kernel<<<dim3(2176), 256, 0, stream>>>((float4*)qp, (float4*)qkb);
    wt_kernel<<<dim3(16), 256, 0, stream>>>(w_qkvl, wT);
    part1_kernel<<<dim3(kB * 128), 256, 0, stream>>>(x, w_hw, b_hw, w_w, b_w, w_h, b_h, out);
    conv1x1_kernel<<<dim3(16, 4, kB), 256, 0, stream>>>(x, wT, b_qkvl, qp, kp, out);
    qk_partial_kernel<<<dim3(8, kB), 256, 0, stream>>>(qp, kp, qkb);
    softmax_kernel<<<dim3(kB), 256, 0, stream>>>(qkb, attn);
    out2_kernel<<<dim3(16, kB), 256, 0, stream>>>(attn, out);
}